// Round 11
// baseline (11432.122 us; speedup 1.0000x reference)
//
#include <hip/hip_runtime.h>
#include <hip/hip_bf16.h>
#include <hip/hip_fp16.h>

#define D     1024
#define D2    2048
#define S_LEN 2048
#define RANK  32
#define DFF   2816
#define EPS_F 1.1920929e-07f
#define T_IT  16        // tokens per workgroup, iteration kernel
#define T_FN  8         // tokens per workgroup, final kernel
#define ZPAD  1032      // 1024 + 8
#define FPAD  2824      // 2816 + 8

typedef unsigned short u16;
typedef unsigned int   u32;

__device__ __forceinline__ void unpack2(u32 u, float& lo, float& hi) {
    union { float f; u32 i; } a, b;
    a.i = u << 16;           // element 0 (low 16 bits)
    b.i = u & 0xFFFF0000u;   // element 1 (high 16 bits)
    lo = a.f; hi = b.f;
}

struct f8 { float v[8]; };
struct __align__(16) h8 { __half h[8]; };
struct __align__(8)  h4 { __half h[4]; };

// load 8 consecutive elements (as fp32) starting at element offset `off`
template<bool F32>
__device__ __forceinline__ f8 load8(const void* base, size_t off) {
    f8 r;
    if (F32) {
        const float4* p = (const float4*)((const float*)base + off);
        float4 a = p[0], b = p[1];
        r.v[0]=a.x; r.v[1]=a.y; r.v[2]=a.z; r.v[3]=a.w;
        r.v[4]=b.x; r.v[5]=b.y; r.v[6]=b.z; r.v[7]=b.w;
    } else {
        uint4 u = *(const uint4*)((const u16*)base + off);
        unpack2(u.x, r.v[0], r.v[1]); unpack2(u.y, r.v[2], r.v[3]);
        unpack2(u.z, r.v[4], r.v[5]); unpack2(u.w, r.v[6], r.v[7]);
    }
    return r;
}

// LDS fp16 -> 8x fp32 (one ds_read_b128 + 8 cvt)
__device__ __forceinline__ f8 load8h(const __half* p) {
    h8 t = *(const h8*)p;
    f8 r;
    #pragma unroll
    for (int k = 0; k < 8; ++k) r.v[k] = __half2float(t.h[k]);
    return r;
}

template<bool F32>
__device__ __forceinline__ void load4(const void* base, size_t off,
                                      float& a0, float& a1, float& a2, float& a3) {
    if (F32) {
        float4 v = *(const float4*)((const float*)base + off);
        a0 = v.x; a1 = v.y; a2 = v.z; a3 = v.w;
    } else {
        uint2 v = *(const uint2*)((const u16*)base + off);
        unpack2(v.x, a0, a1); unpack2(v.y, a2, a3);
    }
}

template<bool F32>
__device__ __forceinline__ void load2(const void* base, size_t off, float& a0, float& a1) {
    if (F32) {
        float2 v = *(const float2*)((const float*)base + off);
        a0 = v.x; a1 = v.y;
    } else {
        u32 v = *(const u32*)((const u16*)base + off);
        unpack2(v, a0, a1);
    }
}

template<bool F32>
__device__ __forceinline__ float load1(const void* base, size_t off) {
    if (F32) return ((const float*)base)[off];
    u16 u = ((const u16*)base)[off];
    union { float f; u32 i; } a; a.i = ((u32)u) << 16;
    return a.f;
}

template<bool F32>
__device__ __forceinline__ void store1(void* base, size_t off, float v) {
    if (F32) ((float*)base)[off] = v;
    else     ((__hip_bfloat16*)base)[off] = __float2bfloat16(v);
}

__device__ __forceinline__ float dot8g(const f8& w, const float* __restrict__ x) {
    return w.v[0]*x[0] + w.v[1]*x[1] + w.v[2]*x[2] + w.v[3]*x[3]
         + w.v[4]*x[4] + w.v[5]*x[5] + w.v[6]*x[6] + w.v[7]*x[7];
}

__device__ __forceinline__ float dot8f(const f8& w, const f8& x) {
    return w.v[0]*x.v[0] + w.v[1]*x.v[1] + w.v[2]*x.v[2] + w.v[3]*x.v[3]
         + w.v[4]*x.v[4] + w.v[5]*x.v[5] + w.v[6]*x.v[6] + w.v[7]*x.v[7];
}

__device__ __forceinline__ float wave_reduce(float v) {
    #pragma unroll
    for (int off = 1; off < 64; off <<= 1)
        v += __shfl_xor(v, off, 64);
    return v;
}

// ---------------- dtype probe: 1 block ----------------
__global__ void probe_kernel(const u32* __restrict__ x, int* __restrict__ flag) {
    __shared__ int cnt;
    int tid = threadIdx.x;
    if (tid == 0) cnt = 0;
    __syncthreads();
    u32 u = x[tid];
    float lo, hi; unpack2(u, lo, hi);
    int c = 0;
    if (!(fabsf(lo) < 1e4f)) c++;
    if (!(fabsf(hi) < 1e4f)) c++;
    if (c) atomicAdd(&cnt, c);
    __syncthreads();
    if (tid == 0) *flag = (cnt > 16) ? 1 : 0;   // 1 => fp32 storage
}

// ---------------- iteration kernel: T_IT=16 tokens, 512 threads ----------------
// launch_bounds(512,4) clamps VGPR alloc to 64 -> 16 waves/CU (empirical law:
// waves/CU = 1024/VGPR_alloc, alloc quantized {64,128,256}). Body slimmed to
// ~55 live regs: token loops split 2x8 AND weight-matrix passes split, so the
// 64-clamp is benign (R9's spill came from ~120-reg bodies under the clamp).
template<bool F32>
__global__ __launch_bounds__(512, 4) void iter_kernel(
    const int* __restrict__ flag,
    const void* __restrict__ hin, void* __restrict__ hout,
    const void* __restrict__ Wfg, const void* __restrict__ Afg, const void* __restrict__ Bfg,
    const void* __restrict__ Wgu, const void* __restrict__ Agu, const void* __restrict__ Bgu)
{
    if ((*flag != 0) != F32) return;

    __shared__ float Zl[T_IT + 1][ZPAD];   // rmsnorm'd rows t0-1 .. t0+15 (70 KB)
    __shared__ float tl[T_IT][2 * RANK];   // low-rank t per token [fg | gu]
    __shared__ float scl[T_IT + 1];

    const int tid = threadIdx.x;
    const int t0  = blockIdx.x * T_IT;
    const bool first = (t0 & (S_LEN - 1)) == 0;   // first tile of a sequence

    // ---- A: stage h rows (fp32) into LDS; 2 cols/thread ----
    {
        const int c = tid * 2;
        for (int r = 0; r < T_IT + 1; ++r) {
            float a0 = 0.f, a1 = 0.f;
            if (r > 0 || !first)
                load2<F32>(hin, (size_t)(t0 - 1 + r) * D + c, a0, a1);
            Zl[r][c] = a0; Zl[r][c+1] = a1;
        }
    }
    __syncthreads();

    // ---- B: per-row rmsnorm scale ----
    {
        const int wv = tid >> 6, ln = tid & 63;
        for (int r = wv; r < T_IT + 1; r += 8) {
            float ss = 0.f;
            #pragma unroll
            for (int k = 0; k < 4; ++k) {
                const float4 x = *(const float4*)&Zl[r][ln * 4 + k * 256];
                ss += x.x*x.x + x.y*x.y + x.z*x.z + x.w*x.w;
            }
            ss = wave_reduce(ss);
            if (ln == 0) scl[r] = rsqrtf(ss * (1.0f / 1024.0f) + EPS_F);
        }
    }
    __syncthreads();

    // ---- C: normalize in place ----
    {
        const int c = tid * 2;
        for (int r = 0; r < T_IT + 1; ++r) {
            const float s = scl[r];
            float2* p = (float2*)&Zl[r][c];
            float2 x = *p;
            x.x *= s; x.y *= s;
            *p = x;
        }
    }
    __syncthreads();

    // ---- D: tl[t] = [Bfg; Bgu] @ comb_t : 64 rows, 8 threads/row; 2x8 tokens ----
    {
        const int g   = tid >> 3;
        const int sub = tid & 7;
        const void* Bm = (g < RANK) ? Bfg : Bgu;
        const int   gr = (g < RANK) ? g : g - RANK;
        const int   radd   = (sub < 4) ? 1 : 0;
        const int   coloff = (sub & 3) * 256;
        const size_t rbase = (size_t)gr * D2 + sub * 256;

        #pragma unroll 1
        for (int tg = 0; tg < 2; ++tg) {
            const int tb = tg * 8;
            float acc[8];
            #pragma unroll
            for (int tt = 0; tt < 8; ++tt) acc[tt] = 0.f;

            int cc = sub & 31;
            f8 w = load8<F32>(Bm, rbase + cc * 8);
            #pragma unroll 1
            for (int ii = 0; ii < 32; ++ii) {
                const f8 cw = w;
                const int ci = cc;
                if (ii < 31) {
                    cc = (ii + 1 + sub) & 31;
                    w = load8<F32>(Bm, rbase + cc * 8);
                }
                #pragma unroll
                for (int tt = 0; tt < 8; ++tt)
                    acc[tt] += dot8g(cw, &Zl[tb + tt + radd][coloff + ci * 8]);
            }
            #pragma unroll
            for (int tt = 0; tt < 8; ++tt) {
                float v = acc[tt];
                v += __shfl_xor(v, 1, 64);
                v += __shfl_xor(v, 2, 64);
                v += __shfl_xor(v, 4, 64);
                if (sub == 0) tl[tb + tt][g] = v;
            }
        }
    }
    __syncthreads();

    // ---- E: block-diagonal mains; 2x8 tokens, gate/update matrix passes split ----
    #pragma unroll 1
    for (int m = 0; m < 2; ++m) {
        const int o    = tid + m * 512;
        const int b    = o >> 7;
        const int radd = (b < 4) ? 1 : 0;
        const int col  = (b & 3) * 256;
        const size_t w0 = (size_t)o * 256;

        #pragma unroll 1
        for (int tg = 0; tg < 2; ++tg) {
            const int tb = tg * 8;

            // pass 1: gate matrix (Wfg/Afg)
            float af[8];
            #pragma unroll
            for (int tt = 0; tt < 8; ++tt) af[tt] = 0.f;
            {
                f8 w = load8<F32>(Wfg, w0);
                #pragma unroll 1
                for (int i = 0; i < 32; ++i) {
                    const f8 cw = w;
                    if (i < 31) w = load8<F32>(Wfg, w0 + (i + 1) * 8);
                    const int xc = col + i * 8;
                    #pragma unroll
                    for (int tt = 0; tt < 8; ++tt)
                        af[tt] += dot8g(cw, &Zl[tb + tt + radd][xc]);
                }
                #pragma unroll
                for (int rc = 0; rc < 4; ++rc) {
                    const f8 a8 = load8<F32>(Afg, (size_t)o * RANK + rc * 8);
                    #pragma unroll
                    for (int tt = 0; tt < 8; ++tt)
                        af[tt] += dot8g(a8, &tl[tb + tt][rc * 8]);
                }
            }

            // pass 2: update matrix (Wgu/Agu) + epilogue
            float ag[8];
            #pragma unroll
            for (int tt = 0; tt < 8; ++tt) ag[tt] = 0.f;
            {
                f8 w = load8<F32>(Wgu, w0);
                #pragma unroll 1
                for (int i = 0; i < 32; ++i) {
                    const f8 cw = w;
                    if (i < 31) w = load8<F32>(Wgu, w0 + (i + 1) * 8);
                    const int xc = col + i * 8;
                    #pragma unroll
                    for (int tt = 0; tt < 8; ++tt)
                        ag[tt] += dot8g(cw, &Zl[tb + tt + radd][xc]);
                }
                #pragma unroll
                for (int rc = 0; rc < 4; ++rc) {
                    const f8 a8 = load8<F32>(Agu, (size_t)o * RANK + rc * 8);
                    #pragma unroll
                    for (int tt = 0; tt < 8; ++tt)
                        ag[tt] += dot8g(a8, &tl[tb + tt][RANK + rc * 8]);
                }
            }

            #pragma unroll
            for (int tt = 0; tt < 8; ++tt) {
                const float h = load1<F32>(hin, (size_t)(t0 + tb + tt) * D + o);
                const float gate = 1.f / (1.f + __expf(-af[tt]));
                store1<F32>(hout, (size_t)(t0 + tb + tt) * D + o, h + gate * ag[tt]);
            }
        }
    }
}

// ---------------- final kernel: T_FN=8 tokens, 512 threads, fp16 LDS tiles ----
// launch_bounds(512,4): 64-VGPR clamp, slim body (token 2x4 + matrix-pass split).
template<bool F32>
__global__ __launch_bounds__(512, 4) void final_kernel(
    const int* __restrict__ flag,
    const void* __restrict__ hin, void* __restrict__ outp,
    const void* __restrict__ Wg, const void* __restrict__ Ag, const void* __restrict__ Bg,
    const void* __restrict__ Wf, const void* __restrict__ Af, const void* __restrict__ Bf,
    const void* __restrict__ Wp, const void* __restrict__ Ap, const void* __restrict__ Bp)
{
    if ((*flag != 0) != F32) return;

    // manual LDS layout with phase-based aliasing
    //   [0, 16512)        Zh[8][1032] fp16   (live ph1-3)  | part4 float[4096] (ph4)
    //   [16512, 61696)    ffs[8][2824] fp16  (live ph3-5)  | part2 float[4096] (ph2)
    __shared__ __align__(16) char smem[16512 + 45184];
    __half (*Zh)[ZPAD]  = (__half (*)[ZPAD])  smem;
    __half (*ffs)[FPAD] = (__half (*)[FPAD]) (smem + 16512);
    float* part2 = (float*)(smem + 16512);
    float* part4 = (float*)smem;

    __shared__ float tg_[T_FN][RANK];
    __shared__ float tf_[T_FN][RANK];
    __shared__ float tp_[T_FN][RANK];

    const int tid = threadIdx.x;
    const int t0  = blockIdx.x * T_FN;
    const int wv  = tid >> 6;
    const int ln  = tid & 63;

    // ---- 1: rmsnorm, one wave per token; store z as fp16 ----
    {
        float v[16];
        float ss = 0.f;
        #pragma unroll
        for (int k = 0; k < 4; ++k) {
            float a0, a1, a2, a3;
            load4<F32>(hin, (size_t)(t0 + wv) * D + ln * 4 + k * 256, a0, a1, a2, a3);
            v[k*4+0]=a0; v[k*4+1]=a1; v[k*4+2]=a2; v[k*4+3]=a3;
            ss += a0*a0 + a1*a1 + a2*a2 + a3*a3;
        }
        ss = wave_reduce(ss);
        const float sc = rsqrtf(ss * (1.0f / 1024.0f) + EPS_F);
        #pragma unroll
        for (int k = 0; k < 4; ++k) {
            h4 p;
            p.h[0] = __float2half(v[k*4+0]*sc);
            p.h[1] = __float2half(v[k*4+1]*sc);
            p.h[2] = __float2half(v[k*4+2]*sc);
            p.h[3] = __float2half(v[k*4+3]*sc);
            *(h4*)&Zh[wv][ln * 4 + k * 256] = p;
        }
    }
    __syncthreads();

    // ---- 2: tg/tf partials: wave = 128-col strip, lane = row; 2x4 tokens ----
    {
        const void* Bm = (ln < RANK) ? Bg : Bf;
        const int   gr = (ln < RANK) ? ln : ln - RANK;
        #pragma unroll 1
        for (int tgp = 0; tgp < 2; ++tgp) {
            const int tb = tgp * 4;
            float acc[4];
            #pragma unroll
            for (int tt = 0; tt < 4; ++tt) acc[tt] = 0.f;
            for (int cc = 0; cc < 16; ++cc) {
                const int c = wv * 128 + cc * 8;
                const f8 w = load8<F32>(Bm, (size_t)gr * D + c);
                #pragma unroll
                for (int tt = 0; tt < 4; ++tt) {
                    const f8 x = load8h(&Zh[tb + tt][c]);   // wave-uniform
                    acc[tt] += dot8f(w, x);
                }
            }
            #pragma unroll
            for (int tt = 0; tt < 4; ++tt)
                part2[(wv * 8 + tb + tt) * 64 + ln] = acc[tt];
        }
    }
    __syncthreads();
    {
        const int t = tid >> 6, g = tid & 63;
        float s = 0.f;
        #pragma unroll
        for (int w = 0; w < 8; ++w) s += part2[(w * 8 + t) * 64 + g];
        if (g < RANK) tg_[t][g] = s; else tf_[t][g - RANK] = s;
    }
    __syncthreads();

    // ---- 3: ff = silu(gate) * lin ; 2x4 tokens, gate/lin matrix passes split ----
    #pragma unroll 1
    for (int m = 0; m < 6; ++m) {
        const int j = tid + m * 512;
        if (j < DFF) {
            const int b  = j / 352;
            const int cb = b * 128;
            const size_t wr = (size_t)j * 128;
            #pragma unroll 1
            for (int tgp = 0; tgp < 2; ++tgp) {
                const int tb = tgp * 4;

                // pass 1: gate matrix (Wg/Ag)
                float ag_[4];
                #pragma unroll
                for (int tt = 0; tt < 4; ++tt) ag_[tt] = 0.f;
                {
                    f8 w = load8<F32>(Wg, wr);
                    #pragma unroll 1
                    for (int i = 0; i < 16; ++i) {
                        const f8 cw = w;
                        if (i < 15) w = load8<F32>(Wg, wr + (i + 1) * 8);
                        #pragma unroll
                        for (int tt = 0; tt < 4; ++tt) {
                            const f8 x = load8h(&Zh[tb + tt][cb + i * 8]);
                            ag_[tt] += dot8f(cw, x);
                        }
                    }
                    #pragma unroll
                    for (int rc = 0; rc < 4; ++rc) {
                        const f8 a8 = load8<F32>(Ag, (size_t)j * RANK + rc * 8);
                        #pragma unroll
                        for (int tt = 0; tt < 4; ++tt)
                            ag_[tt] += dot8g(a8, &tg_[tb + tt][rc * 8]);
                    }
                }

                // pass 2: lin matrix (Wf/Af) + combine
                float af_[4];
                #pragma unroll
                for (int tt = 0; tt < 4; ++tt) af_[tt] = 0.f;
                {
                    f8 w = load8<F32>(Wf, wr);
                    #pragma unroll 1
                    for (int i = 0; i < 16; ++i) {
                        const f8 cw = w;
                        if (i < 15) w = load8<F32>(Wf, wr + (i + 1) * 8);
                        #pragma unroll
                        for (int tt = 0; tt < 4; ++tt) {
                            const f8 x = load8h(&Zh[tb + tt][cb + i * 8]);
                            af_[tt] += dot8f(cw, x);
                        }
                    }
                    #pragma unroll
                    for (int rc = 0; rc < 4; ++rc) {
                        const f8 a8 = load8<F32>(Af, (size_t)j * RANK + rc * 8);
                        #pragma unroll
                        for (int tt = 0; tt < 4; ++tt)
                            af_[tt] += dot8g(a8, &tf_[tb + tt][rc * 8]);
                    }
                }

                #pragma unroll
                for (int tt = 0; tt < 4; ++tt) {
                    const float a = ag_[tt];
                    ffs[tb + tt][j] = __float2half((a / (1.f + __expf(-a))) * af_[tt]);
                }
            }
        }
    }
    __syncthreads();

    // ---- 4: tp partials: row r, column interleave seg; 2x4 tokens ----
    {
        const int seg = tid >> 5, r = tid & 31;
        #pragma unroll 1
        for (int tgp = 0; tgp < 2; ++tgp) {
            const int tb = tgp * 4;
            float acc[4];
            #pragma unroll
            for (int tt = 0; tt < 4; ++tt) acc[tt] = 0.f;
            for (int cc = 0; cc < 22; ++cc) {
                const int c = seg * 8 + cc * 128;
                const f8 w = load8<F32>(Bp, (size_t)r * DFF + c);
                #pragma unroll
                for (int tt = 0; tt < 4; ++tt) {
                    const f8 x = load8h(&ffs[tb + tt][c]);
                    acc[tt] += dot8f(w, x);
                }
            }
            #pragma unroll
            for (int tt = 0; tt < 4; ++tt)
                part4[(seg * 8 + tb + tt) * 32 + r] = acc[tt];
        }
    }
    __syncthreads();
    if (tid < 256) {
        const int t = tid >> 5, r = tid & 31;
        float s = 0.f;
        #pragma unroll
        for (int sg = 0; sg < 16; ++sg) s += part4[(sg * 8 + t) * 32 + r];
        tp_[t][r] = s;
    }
    __syncthreads();

    // ---- 5: out = h + blockdiag(Wp)@ff + Ap@tp ; 2x4 tokens ----
    #pragma unroll 1
    for (int m = 0; m < 2; ++m) {
        const int o = tid + m * 512;
        const int b = o >> 7;
        const size_t wr = (size_t)o * 352;
        #pragma unroll 1
        for (int tgp = 0; tgp < 2; ++tgp) {
            const int tb = tgp * 4;
            float acc[4];
            #pragma unroll
            for (int tt = 0; tt < 4; ++tt) acc[tt] = 0.f;
            f8 w = load8<F32>(Wp, wr);
            #pragma unroll 1
            for (int i = 0; i < 44; ++i) {
                const f8 cw = w;
                if (i < 43) w = load8<F32>(Wp, wr + (i + 1) * 8);
                #pragma unroll
                for (int tt = 0; tt < 4; ++tt) {
                    const f8 x = load8h(&ffs[tb + tt][b * 352 + i * 8]);
                    acc[tt] += dot8f(cw, x);
                }
            }
            #pragma unroll
            for (int rc = 0; rc < 4; ++rc) {
                const f8 a8 = load8<F32>(Ap, (size_t)o * RANK + rc * 8);
                #pragma unroll
                for (int tt = 0; tt < 4; ++tt)
                    acc[tt] += dot8g(a8, &tp_[tb + tt][rc * 8]);
            }
            #pragma unroll
            for (int tt = 0; tt < 4; ++tt) {
                const float h = load1<F32>(hin, (size_t)(t0 + tb + tt) * D + o);
                store1<F32>(outp, (size_t)(t0 + tb + tt) * D + o, h + acc[tt]);
            }
        }
    }
}

extern "C" void kernel_launch(void* const* d_in, const int* in_sizes, int n_in,
                              void* d_out, int out_size, void* d_ws, size_t ws_size,
                              hipStream_t stream) {
    const void* x     = d_in[0];
    const void* fg_W  = d_in[1];
    const void* fg_A  = d_in[2];
    const void* fg_B  = d_in[3];
    const void* gu_W  = d_in[4];
    const void* gu_A  = d_in[5];
    const void* gu_B  = d_in[6];
    const void* ffg_W = d_in[7];
    const void* ffg_A = d_in[8];
    const void* ffg_B = d_in[9];
    const void* fff_W = d_in[10];
    const void* fff_A = d_in[11];
    const void* fff_B = d_in[12];
    const void* ffp_W = d_in[13];
    const void* ffp_A = d_in[14];
    const void* ffp_B = d_in[15];

    int*  flag = (int*)d_ws;
    void* h1   = (void*)((char*)d_ws + 1024);   // up to 64 MiB (fp32 case)
    void* hout = d_out;

    const int n_tok = 8 * S_LEN;   // 16384

    probe_kernel<<<1, 256, 0, stream>>>((const u32*)x, flag);

    // ping-pong: x -> h1 -> out -> h1 -> out, then final(out -> out in place)
    // Launch both dtype variants per stage; the wrong one early-exits on flag.
    #define ITER(SRC, DST) \
        iter_kernel<false><<<n_tok / T_IT, 512, 0, stream>>>(flag, SRC, DST, fg_W, fg_A, fg_B, gu_W, gu_A, gu_B); \
        iter_kernel<true ><<<n_tok / T_IT, 512, 0, stream>>>(flag, SRC, DST, fg_W, fg_A, fg_B, gu_W, gu_A, gu_B);

    ITER(x,    h1)
    ITER(h1,   hout)
    ITER(hout, h1)
    ITER(h1,   hout)
    #undef ITER

    final_kernel<false><<<n_tok / T_FN, 512, 0, stream>>>(flag, hout, hout,
                                                          ffg_W, ffg_A, ffg_B,
                                                          fff_W, fff_A, fff_B,
                                                          ffp_W, ffp_A, ffp_B);
    final_kernel<true ><<<n_tok / T_FN, 512, 0, stream>>>(flag, hout, hout,
                                                          ffg_W, ffg_A, ffg_B,
                                                          fff_W, fff_A, fff_B,
                                                          ffp_W, ffp_A, ffp_B);
}

// Round 12
// 4491.137 us; speedup vs baseline: 2.5455x; 2.5455x over previous
//
#include <hip/hip_runtime.h>
#include <hip/hip_bf16.h>
#include <hip/hip_fp16.h>

#define D     1024
#define D2    2048
#define S_LEN 2048
#define RANK  32
#define DFF   2816
#define EPS_F 1.1920929e-07f
#define T_IT  16        // tokens per workgroup, iteration kernel
#define T_FN  8         // tokens per workgroup, final kernel
#define ZPAD  1032      // 1024 + 8
#define FPAD  2824      // 2816 + 8

typedef unsigned short u16;
typedef unsigned int   u32;
typedef __fp16 hh2 __attribute__((ext_vector_type(2)));

__device__ __forceinline__ void unpack2(u32 u, float& lo, float& hi) {
    union { float f; u32 i; } a, b;
    a.i = u << 16;           // element 0 (low 16 bits)
    b.i = u & 0xFFFF0000u;   // element 1 (high 16 bits)
    lo = a.f; hi = b.f;
}

struct f8 { float v[8]; };
struct __align__(16) hv8 { hh2 p[4]; };   // 8 fp16 in 4 VGPRs
struct __align__(8)  h4 { __half h[4]; };

// load 8 consecutive elements (as fp32) starting at element offset `off`
template<bool F32>
__device__ __forceinline__ f8 load8(const void* base, size_t off) {
    f8 r;
    if (F32) {
        const float4* p = (const float4*)((const float*)base + off);
        float4 a = p[0], b = p[1];
        r.v[0]=a.x; r.v[1]=a.y; r.v[2]=a.z; r.v[3]=a.w;
        r.v[4]=b.x; r.v[5]=b.y; r.v[6]=b.z; r.v[7]=b.w;
    } else {
        uint4 u = *(const uint4*)((const u16*)base + off);
        unpack2(u.x, r.v[0], r.v[1]); unpack2(u.y, r.v[2], r.v[3]);
        unpack2(u.z, r.v[4], r.v[5]); unpack2(u.w, r.v[6], r.v[7]);
    }
    return r;
}

// pack f8 (fp32 regs) -> 8x fp16 (4 VGPRs); amortized once per weight load
__device__ __forceinline__ hv8 cvt8h(const f8& w) {
    hv8 r;
    #pragma unroll
    for (int k = 0; k < 4; ++k) {
        hh2 t;
        t[0] = (__fp16)w.v[2*k];
        t[1] = (__fp16)w.v[2*k+1];
        r.p[k] = t;
    }
    return r;
}

// LDS fp16 x-tile: one ds_read_b128, no converts
__device__ __forceinline__ hv8 loadh8(const __half* p) {
    return *(const hv8*)p;
}

// 8-term fp16 dot with f32 accumulate: 4 x v_dot2_f32_f16
__device__ __forceinline__ float dot8h(const hv8& w, const hv8& x, float acc) {
#if __has_builtin(__builtin_amdgcn_fdot2)
    acc = __builtin_amdgcn_fdot2(w.p[0], x.p[0], acc, false);
    acc = __builtin_amdgcn_fdot2(w.p[1], x.p[1], acc, false);
    acc = __builtin_amdgcn_fdot2(w.p[2], x.p[2], acc, false);
    acc = __builtin_amdgcn_fdot2(w.p[3], x.p[3], acc, false);
#else
    #pragma unroll
    for (int k = 0; k < 4; ++k)
        acc += (float)w.p[k][0]*(float)x.p[k][0] + (float)w.p[k][1]*(float)x.p[k][1];
#endif
    return acc;
}

template<bool F32>
__device__ __forceinline__ void load4(const void* base, size_t off,
                                      float& a0, float& a1, float& a2, float& a3) {
    if (F32) {
        float4 v = *(const float4*)((const float*)base + off);
        a0 = v.x; a1 = v.y; a2 = v.z; a3 = v.w;
    } else {
        uint2 v = *(const uint2*)((const u16*)base + off);
        unpack2(v.x, a0, a1); unpack2(v.y, a2, a3);
    }
}

template<bool F32>
__device__ __forceinline__ void load2(const void* base, size_t off, float& a0, float& a1) {
    if (F32) {
        float2 v = *(const float2*)((const float*)base + off);
        a0 = v.x; a1 = v.y;
    } else {
        u32 v = *(const u32*)((const u16*)base + off);
        unpack2(v, a0, a1);
    }
}

template<bool F32>
__device__ __forceinline__ float load1(const void* base, size_t off) {
    if (F32) return ((const float*)base)[off];
    u16 u = ((const u16*)base)[off];
    union { float f; u32 i; } a; a.i = ((u32)u) << 16;
    return a.f;
}

template<bool F32>
__device__ __forceinline__ void store1(void* base, size_t off, float v) {
    if (F32) ((float*)base)[off] = v;
    else     ((__hip_bfloat16*)base)[off] = __float2bfloat16(v);
}

__device__ __forceinline__ float dot8g(const f8& w, const float* __restrict__ x) {
    return w.v[0]*x[0] + w.v[1]*x[1] + w.v[2]*x[2] + w.v[3]*x[3]
         + w.v[4]*x[4] + w.v[5]*x[5] + w.v[6]*x[6] + w.v[7]*x[7];
}

__device__ __forceinline__ float wave_reduce(float v) {
    #pragma unroll
    for (int off = 1; off < 64; off <<= 1)
        v += __shfl_xor(v, off, 64);
    return v;
}

// ---------------- dtype probe: 1 block ----------------
__global__ void probe_kernel(const u32* __restrict__ x, int* __restrict__ flag) {
    __shared__ int cnt;
    int tid = threadIdx.x;
    if (tid == 0) cnt = 0;
    __syncthreads();
    u32 u = x[tid];
    float lo, hi; unpack2(u, lo, hi);
    int c = 0;
    if (!(fabsf(lo) < 1e4f)) c++;
    if (!(fabsf(hi) < 1e4f)) c++;
    if (c) atomicAdd(&cnt, c);
    __syncthreads();
    if (tid == 0) *flag = (cnt > 16) ? 1 : 0;   // 1 => fp32 storage
}

// ---------------- iteration kernel: T_IT=16 tokens, 512 threads ----------------
// R7 structure; Zl stored fp16 (LDS 70->35 KB), inner dots via v_dot2_f32_f16.
template<bool F32>
__global__ __launch_bounds__(512, 2) void iter_kernel(
    const int* __restrict__ flag,
    const void* __restrict__ hin, void* __restrict__ hout,
    const void* __restrict__ Wfg, const void* __restrict__ Afg, const void* __restrict__ Bfg,
    const void* __restrict__ Wgu, const void* __restrict__ Agu, const void* __restrict__ Bgu)
{
    if ((*flag != 0) != F32) return;

    __shared__ __half Zl[T_IT + 1][ZPAD];  // rmsnorm'd rows t0-1..t0+15, fp16 (35 KB)
    __shared__ float tl[T_IT][2 * RANK];   // low-rank t per token [fg | gu]
    __shared__ float scl[T_IT + 1];

    const int tid = threadIdx.x;
    const int t0  = blockIdx.x * T_IT;
    const bool first = (t0 & (S_LEN - 1)) == 0;   // first tile of a sequence

    // ---- A: stage h rows into LDS as fp16; 2 cols/thread ----
    {
        const int c = tid * 2;
        for (int r = 0; r < T_IT + 1; ++r) {
            float a0 = 0.f, a1 = 0.f;
            if (r > 0 || !first)
                load2<F32>(hin, (size_t)(t0 - 1 + r) * D + c, a0, a1);
            hh2 pk; pk[0] = (__fp16)a0; pk[1] = (__fp16)a1;
            *(hh2*)&Zl[r][c] = pk;
        }
    }
    __syncthreads();

    // ---- B: per-row rmsnorm scale (self-dot via fdot2) ----
    {
        const int wv = tid >> 6, ln = tid & 63;
        for (int r = wv; r < T_IT + 1; r += 8) {
            float ss = 0.f;
            #pragma unroll
            for (int k = 0; k < 2; ++k) {
                const hv8 x = loadh8(&Zl[r][ln * 8 + k * 512]);
                ss = dot8h(x, x, ss);
            }
            ss = wave_reduce(ss);
            if (ln == 0) scl[r] = rsqrtf(ss * (1.0f / 1024.0f) + EPS_F);
        }
    }
    __syncthreads();

    // ---- C: normalize in place ----
    {
        const int c = tid * 2;
        for (int r = 0; r < T_IT + 1; ++r) {
            const float s = scl[r];
            hh2 v = *(hh2*)&Zl[r][c];
            hh2 o; o[0] = (__fp16)((float)v[0] * s); o[1] = (__fp16)((float)v[1] * s);
            *(hh2*)&Zl[r][c] = o;
        }
    }
    __syncthreads();

    // ---- D: tl[t] = [Bfg; Bgu] @ comb_t : 64 rows, 8 threads/row ----
    {
        const int g   = tid >> 3;
        const int sub = tid & 7;
        const void* Bm = (g < RANK) ? Bfg : Bgu;
        const int   gr = (g < RANK) ? g : g - RANK;
        const int   radd   = (sub < 4) ? 1 : 0;
        const int   coloff = (sub & 3) * 256;
        const size_t rbase = (size_t)gr * D2 + sub * 256;

        float acc[T_IT];
        #pragma unroll
        for (int t = 0; t < T_IT; ++t) acc[t] = 0.f;

        int cc = sub & 31;
        f8 w = load8<F32>(Bm, rbase + cc * 8);
        #pragma unroll 1
        for (int ii = 0; ii < 32; ++ii) {
            const hv8 cw = cvt8h(w);
            const int ci = cc;
            if (ii < 31) {
                cc = (ii + 1 + sub) & 31;
                w = load8<F32>(Bm, rbase + cc * 8);
            }
            #pragma unroll
            for (int t = 0; t < T_IT; ++t)
                acc[t] = dot8h(cw, loadh8(&Zl[t + radd][coloff + ci * 8]), acc[t]);
        }
        #pragma unroll
        for (int t = 0; t < T_IT; ++t) {
            float v = acc[t];
            v += __shfl_xor(v, 1, 64);
            v += __shfl_xor(v, 2, 64);
            v += __shfl_xor(v, 4, 64);
            if (sub == 0) tl[t][g] = v;
        }
    }
    __syncthreads();

    // ---- E: block-diagonal mains + A-term + epilogue ----
    #pragma unroll 1
    for (int m = 0; m < 2; ++m) {
        const int o    = tid + m * 512;
        const int b    = o >> 7;
        const int radd = (b < 4) ? 1 : 0;
        const int col  = (b & 3) * 256;
        const size_t w0 = (size_t)o * 256;

        float af[T_IT], ag[T_IT];
        #pragma unroll
        for (int t = 0; t < T_IT; ++t) { af[t]=0.f; ag[t]=0.f; }

        f8 wfr = load8<F32>(Wfg, w0);
        f8 wgr = load8<F32>(Wgu, w0);
        #pragma unroll 1
        for (int i = 0; i < 32; ++i) {
            const hv8 cf = cvt8h(wfr), cg = cvt8h(wgr);
            if (i < 31) {   // prefetch next weight chunks (hides L2 latency)
                const int off = (i + 1) * 8;
                wfr = load8<F32>(Wfg, w0 + off);
                wgr = load8<F32>(Wgu, w0 + off);
            }
            const int xc = col + i * 8;
            #pragma unroll
            for (int t = 0; t < T_IT; ++t) {
                const hv8 x = loadh8(&Zl[t + radd][xc]);   // wave-uniform -> broadcast
                af[t] = dot8h(cf, x, af[t]);
                ag[t] = dot8h(cg, x, ag[t]);
            }
        }

        #pragma unroll
        for (int rc = 0; rc < 4; ++rc) {
            const f8 a_f = load8<F32>(Afg, (size_t)o * RANK + rc * 8);
            const f8 a_g = load8<F32>(Agu, (size_t)o * RANK + rc * 8);
            #pragma unroll
            for (int t = 0; t < T_IT; ++t) {
                af[t] += dot8g(a_f, &tl[t][rc * 8]);
                ag[t] += dot8g(a_g, &tl[t][RANK + rc * 8]);
            }
        }

        #pragma unroll
        for (int t = 0; t < T_IT; ++t) {
            const float h = load1<F32>(hin, (size_t)(t0 + t) * D + o);
            const float gate = 1.f / (1.f + __expf(-af[t]));
            store1<F32>(hout, (size_t)(t0 + t) * D + o, h + gate * ag[t]);
        }
    }
}

// ---------------- final kernel: T_FN=8 tokens, 512 threads, fp16 LDS tiles ----
// R7 structure (best measured); all big dots via v_dot2_f32_f16.
template<bool F32>
__global__ __launch_bounds__(512, 2) void final_kernel(
    const int* __restrict__ flag,
    const void* __restrict__ hin, void* __restrict__ outp,
    const void* __restrict__ Wg, const void* __restrict__ Ag, const void* __restrict__ Bg,
    const void* __restrict__ Wf, const void* __restrict__ Af, const void* __restrict__ Bf,
    const void* __restrict__ Wp, const void* __restrict__ Ap, const void* __restrict__ Bp)
{
    if ((*flag != 0) != F32) return;

    // manual LDS layout with phase-based aliasing
    //   [0, 16512)        Zh[8][1032] fp16   (live ph1-3)  | part4 float[4096] (ph4)
    //   [16512, 61696)    ffs[8][2824] fp16  (live ph3-5)  | part2 float[4096] (ph2)
    __shared__ __align__(16) char smem[16512 + 45184];
    __half (*Zh)[ZPAD]  = (__half (*)[ZPAD])  smem;
    __half (*ffs)[FPAD] = (__half (*)[FPAD]) (smem + 16512);
    float* part2 = (float*)(smem + 16512);
    float* part4 = (float*)smem;

    __shared__ float tg_[T_FN][RANK];
    __shared__ float tf_[T_FN][RANK];
    __shared__ float tp_[T_FN][RANK];

    const int tid = threadIdx.x;
    const int t0  = blockIdx.x * T_FN;
    const int wv  = tid >> 6;
    const int ln  = tid & 63;

    // ---- 1: rmsnorm, one wave per token; store z as fp16 ----
    {
        float v[16];
        float ss = 0.f;
        #pragma unroll
        for (int k = 0; k < 4; ++k) {
            float a0, a1, a2, a3;
            load4<F32>(hin, (size_t)(t0 + wv) * D + ln * 4 + k * 256, a0, a1, a2, a3);
            v[k*4+0]=a0; v[k*4+1]=a1; v[k*4+2]=a2; v[k*4+3]=a3;
            ss += a0*a0 + a1*a1 + a2*a2 + a3*a3;
        }
        ss = wave_reduce(ss);
        const float sc = rsqrtf(ss * (1.0f / 1024.0f) + EPS_F);
        #pragma unroll
        for (int k = 0; k < 4; ++k) {
            h4 p;
            p.h[0] = __float2half(v[k*4+0]*sc);
            p.h[1] = __float2half(v[k*4+1]*sc);
            p.h[2] = __float2half(v[k*4+2]*sc);
            p.h[3] = __float2half(v[k*4+3]*sc);
            *(h4*)&Zh[wv][ln * 4 + k * 256] = p;
        }
    }
    __syncthreads();

    // ---- 2: tg/tf partials: wave = 128-col strip, lane = row ----
    {
        const void* Bm = (ln < RANK) ? Bg : Bf;
        const int   gr = (ln < RANK) ? ln : ln - RANK;
        float acc[T_FN];
        #pragma unroll
        for (int t = 0; t < T_FN; ++t) acc[t] = 0.f;
        for (int cc = 0; cc < 16; ++cc) {
            const int c = wv * 128 + cc * 8;
            const hv8 w = cvt8h(load8<F32>(Bm, (size_t)gr * D + c));
            #pragma unroll
            for (int t = 0; t < T_FN; ++t)
                acc[t] = dot8h(w, loadh8(&Zh[t][c]), acc[t]);   // broadcast
        }
        #pragma unroll
        for (int t = 0; t < T_FN; ++t)
            part2[(wv * 8 + t) * 64 + ln] = acc[t];
    }
    __syncthreads();
    {
        const int t = tid >> 6, g = tid & 63;
        float s = 0.f;
        #pragma unroll
        for (int w = 0; w < 8; ++w) s += part2[(w * 8 + t) * 64 + g];
        if (g < RANK) tg_[t][g] = s; else tf_[t][g - RANK] = s;
    }
    __syncthreads();

    // ---- 3: ff = silu(gate) * lin ; 2816 outputs over 512 threads ----
    #pragma unroll 1
    for (int m = 0; m < 6; ++m) {
        const int j = tid + m * 512;
        if (j < DFF) {
            const int b  = j / 352;
            const int cb = b * 128;
            const size_t wr = (size_t)j * 128;
            float ag_[T_FN], af_[T_FN];
            #pragma unroll
            for (int t = 0; t < T_FN; ++t) { ag_[t] = 0.f; af_[t] = 0.f; }
            f8 wg8 = load8<F32>(Wg, wr), wf8 = load8<F32>(Wf, wr);
            #pragma unroll 1
            for (int i = 0; i < 16; ++i) {
                const hv8 cg = cvt8h(wg8), cf = cvt8h(wf8);
                if (i < 15) {
                    wg8 = load8<F32>(Wg, wr + (i + 1) * 8);
                    wf8 = load8<F32>(Wf, wr + (i + 1) * 8);
                }
                #pragma unroll
                for (int t = 0; t < T_FN; ++t) {
                    const hv8 x = loadh8(&Zh[t][cb + i * 8]);
                    ag_[t] = dot8h(cg, x, ag_[t]);
                    af_[t] = dot8h(cf, x, af_[t]);
                }
            }
            #pragma unroll
            for (int rc = 0; rc < 4; ++rc) {
                const f8 a_g = load8<F32>(Ag, (size_t)j * RANK + rc * 8);
                const f8 a_f = load8<F32>(Af, (size_t)j * RANK + rc * 8);
                #pragma unroll
                for (int t = 0; t < T_FN; ++t) {
                    ag_[t] += dot8g(a_g, &tg_[t][rc * 8]);
                    af_[t] += dot8g(a_f, &tf_[t][rc * 8]);
                }
            }
            #pragma unroll
            for (int t = 0; t < T_FN; ++t) {
                const float a = ag_[t];
                ffs[t][j] = __float2half((a / (1.f + __expf(-a))) * af_[t]);
            }
        }
    }
    __syncthreads();

    // ---- 4: tp partials: row r, column interleave seg (part4 aliases dead Zh) ----
    {
        const int seg = tid >> 5, r = tid & 31;
        float acc[T_FN];
        #pragma unroll
        for (int t = 0; t < T_FN; ++t) acc[t] = 0.f;
        for (int cc = 0; cc < 22; ++cc) {
            const int c = seg * 8 + cc * 128;
            const hv8 w = cvt8h(load8<F32>(Bp, (size_t)r * DFF + c));
            #pragma unroll
            for (int t = 0; t < T_FN; ++t)
                acc[t] = dot8h(w, loadh8(&ffs[t][c]), acc[t]);
        }
        #pragma unroll
        for (int t = 0; t < T_FN; ++t)
            part4[(seg * 8 + t) * 32 + r] = acc[t];
    }
    __syncthreads();
    if (tid < 256) {
        const int t = tid >> 5, r = tid & 31;
        float s = 0.f;
        #pragma unroll
        for (int sg = 0; sg < 16; ++sg) s += part4[(sg * 8 + t) * 32 + r];
        tp_[t][r] = s;
    }
    __syncthreads();

    // ---- 5: out = h + blockdiag(Wp)@ff + Ap@tp ; 1 row/thread/m ----
    #pragma unroll 1
    for (int m = 0; m < 2; ++m) {
        const int o = tid + m * 512;
        const int b = o >> 7;
        const size_t wr = (size_t)o * 352;
        float acc[T_FN];
        #pragma unroll
        for (int t = 0; t < T_FN; ++t) acc[t] = 0.f;
        f8 w = load8<F32>(Wp, wr);
        #pragma unroll 1
        for (int i = 0; i < 44; ++i) {
            const hv8 cw = cvt8h(w);
            if (i < 43) w = load8<F32>(Wp, wr + (i + 1) * 8);
            #pragma unroll
            for (int t = 0; t < T_FN; ++t)
                acc[t] = dot8h(cw, loadh8(&ffs[t][b * 352 + i * 8]), acc[t]);
        }
        #pragma unroll
        for (int rc = 0; rc < 4; ++rc) {
            const f8 a8 = load8<F32>(Ap, (size_t)o * RANK + rc * 8);
            #pragma unroll
            for (int t = 0; t < T_FN; ++t)
                acc[t] += dot8g(a8, &tp_[t][rc * 8]);
        }
        #pragma unroll
        for (int t = 0; t < T_FN; ++t) {
            const float h = load1<F32>(hin, (size_t)(t0 + t) * D + o);
            store1<F32>(outp, (size_t)(t0 + t) * D + o, h + acc[t]);
        }
    }
}

extern "C" void kernel_launch(void* const* d_in, const int* in_sizes, int n_in,
                              void* d_out, int out_size, void* d_ws, size_t ws_size,
                              hipStream_t stream) {
    const void* x     = d_in[0];
    const void* fg_W  = d_in[1];
    const void* fg_A  = d_in[2];
    const void* fg_B  = d_in[3];
    const void* gu_W  = d_in[4];
    const void* gu_A  = d_in[5];
    const void* gu_B  = d_in[6];
    const void* ffg_W = d_in[7];
    const void* ffg_A = d_in[8];
    const void* ffg_B = d_in[9];
    const void* fff_W = d_in[10];
    const void* fff_A = d_in[11];
    const void* fff_B = d_in[12];
    const void* ffp_W = d_in[13];
    const void* ffp_A = d_in[14];
    const void* ffp_B = d_in[15];

    int*  flag = (int*)d_ws;
    void* h1   = (void*)((char*)d_ws + 1024);   // up to 64 MiB (fp32 case)
    void* hout = d_out;

    const int n_tok = 8 * S_LEN;   // 16384

    probe_kernel<<<1, 256, 0, stream>>>((const u32*)x, flag);

    // ping-pong: x -> h1 -> out -> h1 -> out, then final(out -> out in place)
    // Launch both dtype variants per stage; the wrong one early-exits on flag.
    #define ITER(SRC, DST) \
        iter_kernel<false><<<n_tok / T_IT, 512, 0, stream>>>(flag, SRC, DST, fg_W, fg_A, fg_B, gu_W, gu_A, gu_B); \
        iter_kernel<true ><<<n_tok / T_IT, 512, 0, stream>>>(flag, SRC, DST, fg_W, fg_A, fg_B, gu_W, gu_A, gu_B);

    ITER(x,    h1)
    ITER(h1,   hout)
    ITER(hout, h1)
    ITER(h1,   hout)
    #undef ITER

    final_kernel<false><<<n_tok / T_FN, 512, 0, stream>>>(flag, hout, hout,
                                                          ffg_W, ffg_A, ffg_B,
                                                          fff_W, fff_A, fff_B,
                                                          ffp_W, ffp_A, ffp_B);
    final_kernel<true ><<<n_tok / T_FN, 512, 0, stream>>>(flag, hout, hout,
                                                          ffg_W, ffg_A, ffg_B,
                                                          fff_W, fff_A, fff_B,
                                                          ffp_W, ffp_A, ffp_B);
}